// Round 3
// baseline (422.255 us; speedup 1.0000x reference)
//
#include <hip/hip_runtime.h>
#include <hip/hip_bf16.h>
#include <stdint.h>

#define B_ 4
#define H_ 16
#define L_ 2048
#define D_ 64
#define BH (B_ * H_)

typedef __attribute__((ext_vector_type(8))) short short8;
typedef __attribute__((ext_vector_type(4))) float f32x4;

__device__ __forceinline__ short b16(float f) {
  __hip_bfloat16 h = __float2bfloat16(f);
  return __builtin_bit_cast(short, h);
}

typedef __attribute__((address_space(1))) const unsigned int guint_t;
typedef __attribute__((address_space(3))) unsigned int luint_t;

__device__ __forceinline__ void glds16(const void* g, void* l) {
  __builtin_amdgcn_global_load_lds((guint_t*)g, (luint_t*)l, 16, 0, 0);
}

// stage one 8KB pre-swizzled tile image (4096 ushorts) into LDS, linear copy
__device__ __forceinline__ void stage_tile(const unsigned short* __restrict__ src,
                                           unsigned short* dst, int t) {
  int w = t >> 6, lane = t & 63;
  glds16(src + w * 1024 + lane * 8,       dst + w * 1024);
  glds16(src + w * 1024 + 512 + lane * 8, dst + w * 1024 + 512);
}

// ---- prepass A: K [bh][k][d] fp32 -> Kb: per (bh,kt) 64x64 bf16 swizzled LDS image ----
__global__ __launch_bounds__(256) void kb_kernel(const float* __restrict__ K,
                                                 unsigned short* __restrict__ Kb) {
  int bid = blockIdx.x;
  int t   = threadIdx.x;
  const float* src = K + (size_t)bid * 64 * D_;   // bid = bh*32+kt, tiles contiguous in k
  unsigned short* dst = Kb + (size_t)bid * 4096;
#pragma unroll
  for (int i = 0; i < 4; ++i) {
    int f4  = i * 256 + t;
    int row = f4 >> 4;
    int c4  = (f4 & 15) << 2;
    float4 v = *reinterpret_cast<const float4*>(src + row * D_ + c4);
    ushort4 u;
    u.x = (unsigned short)b16(v.x);
    u.y = (unsigned short)b16(v.y);
    u.z = (unsigned short)b16(v.z);
    u.w = (unsigned short)b16(v.w);
    *reinterpret_cast<ushort4*>(&dst[row * 64 + (c4 ^ ((row & 7) << 3))]) = u;
  }
}

// ---- prepass B: V [bh][k][d] fp32 -> Vb: per (bh,kt) [d][k] bf16 swizzled LDS image ----
__global__ __launch_bounds__(256) void vtb_kernel(const float* __restrict__ V,
                                                  unsigned short* __restrict__ Vb) {
  __shared__ unsigned short lds[64 * 68];
  int bid = blockIdx.x;
  int t   = threadIdx.x;
  const float* src = V + (size_t)bid * 64 * D_;
#pragma unroll
  for (int i = 0; i < 4; ++i) {
    int f4  = i * 256 + t;
    int row = f4 >> 4;
    int c4  = (f4 & 15) << 2;
    float4 v = *reinterpret_cast<const float4*>(src + row * D_ + c4);
    ushort4 u;
    u.x = (unsigned short)b16(v.x);
    u.y = (unsigned short)b16(v.y);
    u.z = (unsigned short)b16(v.z);
    u.w = (unsigned short)b16(v.w);
    *reinterpret_cast<ushort4*>(&lds[row * 68 + c4]) = u;
  }
  __syncthreads();
  unsigned short* dst = Vb + (size_t)bid * 4096;
#pragma unroll
  for (int i = 0; i < 4; ++i) {
    int g  = i * 256 + t;
    int r  = g >> 4;          // d-row
    int c4 = (g & 15) << 2;   // k-cols
    ushort4 u;
    u.x = lds[(c4 + 0) * 68 + r];
    u.y = lds[(c4 + 1) * 68 + r];
    u.z = lds[(c4 + 2) * 68 + r];
    u.w = lds[(c4 + 3) * 68 + r];
    *reinterpret_cast<ushort4*>(&dst[r * 64 + (c4 ^ ((r & 7) << 3))]) = u;
  }
}

// ---- fused sigmoid-attention, swapped-operand QK^T, glds staging, 2 barriers/iter ----
__global__ __launch_bounds__(256) void attn2_kernel(
    const float* __restrict__ Q, const int* __restrict__ M,
    const unsigned short* __restrict__ Kb, const unsigned short* __restrict__ Vb,
    float* __restrict__ O, float* __restrict__ A) {
  __shared__ __align__(16) unsigned short Kl[2][4096];
  __shared__ __align__(16) unsigned short Vl[2][4096];
  __shared__ __align__(16) unsigned short Pl[4096];

  int wg  = blockIdx.x;
  int swz = (wg & 7) * 256 + (wg >> 3);  // bijective XCD swizzle (2048 % 8 == 0)
  int bh  = swz >> 5;
  int qt  = swz & 31;

  int t    = threadIdx.x;
  int lane = t & 63;
  int w    = t >> 6;
  int wr   = w >> 1;
  int wc   = w & 1;
  int lr   = lane & 15;
  int lg   = lane >> 4;

  // Q fragments (B-operand layout), hoisted
  short8 qf[2][2];
  const float* qbase = Q + ((size_t)bh * L_ + (size_t)qt * 64 + wr * 32) * D_;
#pragma unroll
  for (int m = 0; m < 2; ++m) {
#pragma unroll
    for (int ks = 0; ks < 2; ++ks) {
      const float4* p = reinterpret_cast<const float4*>(qbase + (m * 16 + lr) * D_ + ks * 32 + lg * 8);
      float4 a = p[0], b = p[1];
      qf[m][ks] = (short8){b16(a.x), b16(a.y), b16(a.z), b16(a.w),
                           b16(b.x), b16(b.y), b16(b.z), b16(b.w)};
    }
  }

  f32x4 o[2][2] = {};
  const int* mbase = M + (size_t)(bh >> 4) * L_ * L_;
  float* abase = A + (size_t)bh * L_ * L_;
  const unsigned short* kb = Kb + (size_t)bh * 32 * 4096;
  const unsigned short* vb = Vb + (size_t)bh * 32 * 4096;
  int qrow = qt * 64 + wr * 32;

  // prologue: stage tile 0
  stage_tile(kb, Kl[0], t);
  stage_tile(vb, Vl[0], t);
  __syncthreads();

  for (int ki = 0; ki < 32; ++ki) {
    int cur = ki & 1;
    int k0  = ki * 64;

    // stage next tile (overlaps QK + sigmoid; completes at the mid barrier)
    if (ki + 1 < 32) {
      stage_tile(kb + (size_t)(ki + 1) * 4096, Kl[cur ^ 1], t);
      stage_tile(vb + (size_t)(ki + 1) * 4096, Vl[cur ^ 1], t);
    }

    // mask: one int4 per 16x16 tile
    int4 mv[2][2];
#pragma unroll
    for (int m = 0; m < 2; ++m)
#pragma unroll
      for (int n = 0; n < 2; ++n)
        mv[m][n] = *reinterpret_cast<const int4*>(
            mbase + (size_t)(qrow + m * 16 + lr) * L_ + k0 + wc * 32 + n * 16 + lg * 4);

    // ---- S^T = K Q^T : lane holds 4 consecutive k for one q ----
    f32x4 s[2][2] = {};
#pragma unroll
    for (int ks = 0; ks < 2; ++ks) {
      short8 kf[2];
#pragma unroll
      for (int n = 0; n < 2; ++n) {
        int row = wc * 32 + n * 16 + lr;   // key index
        int col = ks * 32 + lg * 8;        // d
        kf[n] = *reinterpret_cast<const short8*>(&Kl[cur][row * 64 + (col ^ ((row & 7) << 3))]);
      }
#pragma unroll
      for (int m = 0; m < 2; ++m)
#pragma unroll
        for (int n = 0; n < 2; ++n)
          s[m][n] = __builtin_amdgcn_mfma_f32_16x16x32_bf16(kf[n], qf[m][ks], s[m][n], 0, 0, 0);
    }

    // ---- mask + sigmoid; attn f32x4 nt-store; P ushort4 LDS write ----
#pragma unroll
    for (int m = 0; m < 2; ++m) {
#pragma unroll
      for (int n = 0; n < 2; ++n) {
        f32x4 f;
        ushort4 u;
#pragma unroll
        for (int r = 0; r < 4; ++r) {
          float sc = s[m][n][r] * 0.125f;
          float at = ((&mv[m][n].x)[r] != 0)
                         ? __builtin_amdgcn_rcpf(1.0f + __expf(-sc))
                         : 0.0f;
          f[r] = at;
          (&u.x)[r] = (unsigned short)b16(at);
        }
        __builtin_nontemporal_store(f, reinterpret_cast<f32x4*>(
            abase + (size_t)(qrow + m * 16 + lr) * L_ + k0 + wc * 32 + n * 16 + lg * 4));
        int q  = wr * 32 + m * 16 + lr;
        int kl = wc * 32 + n * 16 + lg * 4;
        *reinterpret_cast<ushort4*>(&Pl[q * 64 + (kl ^ ((q & 7) << 3))]) = u;
      }
    }
    __syncthreads();  // P ready + next-tile stage complete

    // ---- O += P V ----
#pragma unroll
    for (int ks = 0; ks < 2; ++ks) {
      short8 pf[2], vf[2];
#pragma unroll
      for (int m = 0; m < 2; ++m) {
        int row = wr * 32 + m * 16 + lr;   // q
        int col = ks * 32 + lg * 8;        // k
        pf[m] = *reinterpret_cast<const short8*>(&Pl[row * 64 + (col ^ ((row & 7) << 3))]);
      }
#pragma unroll
      for (int n = 0; n < 2; ++n) {
        int row = wc * 32 + n * 16 + lr;   // d
        int col = ks * 32 + lg * 8;        // k
        vf[n] = *reinterpret_cast<const short8*>(&Vl[cur][row * 64 + (col ^ ((row & 7) << 3))]);
      }
#pragma unroll
      for (int m = 0; m < 2; ++m)
#pragma unroll
        for (int n = 0; n < 2; ++n)
          o[m][n] = __builtin_amdgcn_mfma_f32_16x16x32_bf16(pf[m], vf[n], o[m][n], 0, 0, 0);
    }
    __syncthreads();  // PV readers done before next stage overwrites buf[cur]
  }

  float* obase = O + ((size_t)bh * L_ + (size_t)qt * 64 + wr * 32) * D_;
#pragma unroll
  for (int m = 0; m < 2; ++m)
#pragma unroll
    for (int n = 0; n < 2; ++n)
#pragma unroll
      for (int r = 0; r < 4; ++r)
        __builtin_nontemporal_store(o[m][n][r],
            &obase[(m * 16 + lg * 4 + r) * D_ + wc * 32 + n * 16 + lr]);
}

// ================= fallback path (R1 kernels, needs only 16.8 MB ws) =================
__global__ __launch_bounds__(256) void vt_kernel(const float* __restrict__ V,
                                                 unsigned short* __restrict__ Vt) {
  __shared__ unsigned short lds[64 * 68];
  int bid = blockIdx.x;
  int bh  = bid >> 5;
  int kt  = bid & 31;
  int t   = threadIdx.x;
  const float* vsrc = V + ((size_t)bh * L_ + (size_t)kt * 64) * D_;
#pragma unroll
  for (int i = 0; i < 4; ++i) {
    int f4  = i * 256 + t;
    int row = f4 >> 4;
    int c4  = (f4 & 15) << 2;
    float4 v = *reinterpret_cast<const float4*>(vsrc + row * D_ + c4);
    ushort4 u;
    u.x = (unsigned short)b16(v.x);
    u.y = (unsigned short)b16(v.y);
    u.z = (unsigned short)b16(v.z);
    u.w = (unsigned short)b16(v.w);
    *reinterpret_cast<ushort4*>(&lds[row * 68 + c4]) = u;
  }
  __syncthreads();
  unsigned short* dst = Vt + (size_t)bh * D_ * L_ + (size_t)kt * 64;
#pragma unroll
  for (int i = 0; i < 8; ++i) {
    int c  = i * 256 + t;
    int d  = c >> 5;
    int k2 = (c & 31) * 2;
    unsigned int lo = lds[(k2 + 0) * 68 + d];
    unsigned int hi = lds[(k2 + 1) * 68 + d];
    *reinterpret_cast<unsigned int*>(dst + d * L_ + k2) = lo | (hi << 16);
  }
}

__global__ __launch_bounds__(256) void attn_kernel(
    const float* __restrict__ Q, const float* __restrict__ K,
    const int* __restrict__ M, const unsigned short* __restrict__ Vt,
    float* __restrict__ O, float* __restrict__ A) {
  __shared__ unsigned short Kl[64 * 64];
  __shared__ unsigned short Vl[64 * 64];
  __shared__ unsigned short Pl[64 * 64];

  int wg  = blockIdx.x;
  int swz = (wg & 7) * 256 + (wg >> 3);
  int bh  = swz >> 5;
  int qt  = swz & 31;

  int t    = threadIdx.x;
  int lane = t & 63;
  int w    = t >> 6;
  int wr   = w >> 1;
  int wc   = w & 1;
  int lr   = lane & 15;
  int lg   = lane >> 4;

  short8 qf[2][2];
  const float* qbase = Q + ((size_t)bh * L_ + (size_t)qt * 64 + wr * 32) * D_;
#pragma unroll
  for (int m = 0; m < 2; ++m) {
#pragma unroll
    for (int ks = 0; ks < 2; ++ks) {
      const float4* p = reinterpret_cast<const float4*>(qbase + (m * 16 + lr) * D_ + ks * 32 + lg * 8);
      float4 a = p[0], b = p[1];
      qf[m][ks] = (short8){b16(a.x), b16(a.y), b16(a.z), b16(a.w),
                           b16(b.x), b16(b.y), b16(b.z), b16(b.w)};
    }
  }

  f32x4 o[2][2] = {};
  const int* mbase = M + (size_t)(bh >> 4) * L_ * L_;
  float* abase = A + (size_t)bh * L_ * L_;
  const float* kbase0 = K + (size_t)bh * L_ * D_;
  const unsigned short* vbase0 = Vt + (size_t)bh * D_ * L_;
  int qrow = qt * 64 + wr * 32;

  for (int ki = 0; ki < 32; ++ki) {
    int k0 = ki * 64;
    int mv[2][2][4];
#pragma unroll
    for (int m = 0; m < 2; ++m)
#pragma unroll
      for (int n = 0; n < 2; ++n)
#pragma unroll
        for (int r = 0; r < 4; ++r)
          mv[m][n][r] = mbase[(size_t)(qrow + m * 16 + lg * 4 + r) * L_ + k0 + wc * 32 + n * 16 + lr];

    __syncthreads();

    const float* ksrc = kbase0 + (size_t)k0 * D_;
#pragma unroll
    for (int i = 0; i < 4; ++i) {
      int f4  = i * 256 + t;
      int row = f4 >> 4;
      int c4  = (f4 & 15) << 2;
      float4 v = *reinterpret_cast<const float4*>(ksrc + row * D_ + c4);
      ushort4 u;
      u.x = (unsigned short)b16(v.x);
      u.y = (unsigned short)b16(v.y);
      u.z = (unsigned short)b16(v.z);
      u.w = (unsigned short)b16(v.w);
      *reinterpret_cast<ushort4*>(&Kl[row * 64 + (c4 ^ ((row & 7) << 3))]) = u;
    }
    const unsigned short* vsrc = vbase0 + k0;
#pragma unroll
    for (int i = 0; i < 2; ++i) {
      int g   = i * 256 + t;
      int row = g >> 3;
      int c0  = (g & 7) << 3;
      uint4 v = *reinterpret_cast<const uint4*>(vsrc + (size_t)row * L_ + c0);
      *reinterpret_cast<uint4*>(&Vl[row * 64 + (c0 ^ ((row & 7) << 3))]) = v;
    }
    __syncthreads();

    f32x4 s[2][2] = {};
#pragma unroll
    for (int ks = 0; ks < 2; ++ks) {
      short8 kf[2];
#pragma unroll
      for (int n = 0; n < 2; ++n) {
        int row = wc * 32 + n * 16 + lr;
        int col = ks * 32 + lg * 8;
        kf[n] = *reinterpret_cast<const short8*>(&Kl[row * 64 + (col ^ ((row & 7) << 3))]);
      }
#pragma unroll
      for (int m = 0; m < 2; ++m)
#pragma unroll
        for (int n = 0; n < 2; ++n)
          s[m][n] = __builtin_amdgcn_mfma_f32_16x16x32_bf16(qf[m][ks], kf[n], s[m][n], 0, 0, 0);
    }

#pragma unroll
    for (int m = 0; m < 2; ++m) {
#pragma unroll
      for (int n = 0; n < 2; ++n) {
        int kcol = k0 + wc * 32 + n * 16 + lr;
        int pq0  = wr * 32 + m * 16 + lg * 4;
        int pk   = wc * 32 + n * 16 + lr;
#pragma unroll
        for (int r = 0; r < 4; ++r) {
          float sc = s[m][n][r] * 0.125f;
          float at = 0.0f;
          if (mv[m][n][r] != 0)
            at = __builtin_amdgcn_rcpf(1.0f + __expf(-sc));
          __builtin_nontemporal_store(at, &abase[(size_t)(qrow + m * 16 + lg * 4 + r) * L_ + kcol]);
          int pq = pq0 + r;
          Pl[pq * 64 + (pk ^ ((pq & 7) << 3))] = (unsigned short)b16(at);
        }
      }
    }
    __syncthreads();

#pragma unroll
    for (int ks = 0; ks < 2; ++ks) {
      short8 pf[2], vf[2];
#pragma unroll
      for (int m = 0; m < 2; ++m) {
        int row = wr * 32 + m * 16 + lr;
        int col = ks * 32 + lg * 8;
        pf[m] = *reinterpret_cast<const short8*>(&Pl[row * 64 + (col ^ ((row & 7) << 3))]);
      }
#pragma unroll
      for (int n = 0; n < 2; ++n) {
        int row = wc * 32 + n * 16 + lr;
        int col = ks * 32 + lg * 8;
        vf[n] = *reinterpret_cast<const short8*>(&Vl[row * 64 + (col ^ ((row & 7) << 3))]);
      }
#pragma unroll
      for (int m = 0; m < 2; ++m)
#pragma unroll
        for (int n = 0; n < 2; ++n)
          o[m][n] = __builtin_amdgcn_mfma_f32_16x16x32_bf16(pf[m], vf[n], o[m][n], 0, 0, 0);
    }
  }

  float* obase = O + ((size_t)bh * L_ + (size_t)qt * 64 + wr * 32) * D_;
#pragma unroll
  for (int m = 0; m < 2; ++m)
#pragma unroll
    for (int n = 0; n < 2; ++n)
#pragma unroll
      for (int r = 0; r < 4; ++r)
        __builtin_nontemporal_store(o[m][n][r],
            &obase[(m * 16 + lg * 4 + r) * D_ + wc * 32 + n * 16 + lr]);
}

extern "C" void kernel_launch(void* const* d_in, const int* in_sizes, int n_in,
                              void* d_out, int out_size, void* d_ws, size_t ws_size,
                              hipStream_t stream) {
  (void)in_sizes; (void)n_in; (void)out_size;
  const float* Q = (const float*)d_in[0];
  const float* K = (const float*)d_in[1];
  const float* V = (const float*)d_in[2];
  const int*   M = (const int*)d_in[3];
  float* O = (float*)d_out;
  float* A = (float*)d_out + (size_t)BH * L_ * D_;

  const size_t tile_bytes = (size_t)BH * 32 * 4096 * 2;  // 16.8 MB per tensor
  if (ws_size >= 2 * tile_bytes) {
    unsigned short* Kb = (unsigned short*)d_ws;
    unsigned short* Vb = (unsigned short*)d_ws + (size_t)BH * 32 * 4096;
    kb_kernel<<<BH * 32, 256, 0, stream>>>(K, Kb);
    vtb_kernel<<<BH * 32, 256, 0, stream>>>(V, Vb);
    attn2_kernel<<<BH * 32, 256, 0, stream>>>(Q, M, Kb, Vb, O, A);
  } else {
    unsigned short* Vt = (unsigned short*)d_ws;
    vt_kernel<<<BH * 32, 256, 0, stream>>>(V, Vt);
    attn_kernel<<<BH * 32, 256, 0, stream>>>(Q, K, M, Vt, O, A);
  }
}

// Round 4
// 319.576 us; speedup vs baseline: 1.3213x; 1.3213x over previous
//
#include <hip/hip_runtime.h>
#include <hip/hip_bf16.h>
#include <stdint.h>

#define B_ 4
#define H_ 16
#define L_ 2048
#define D_ 64
#define BH (B_ * H_)

typedef __attribute__((ext_vector_type(8))) short short8;
typedef __attribute__((ext_vector_type(4))) float f32x4;

__device__ __forceinline__ short b16(float f) {
  __hip_bfloat16 h = __float2bfloat16(f);
  return __builtin_bit_cast(short, h);
}

// ---- prepass: V [bh][k][d] fp32 -> Vt [bh][d][k] bf16 (transposed) ----
__global__ __launch_bounds__(256) void vt_kernel(const float* __restrict__ V,
                                                 unsigned short* __restrict__ Vt) {
  __shared__ unsigned short lds[64 * 68];
  int bid = blockIdx.x;
  int bh  = bid >> 5;
  int kt  = bid & 31;
  int t   = threadIdx.x;
  const float* vsrc = V + ((size_t)bh * L_ + (size_t)kt * 64) * D_;
#pragma unroll
  for (int i = 0; i < 4; ++i) {
    int f4  = i * 256 + t;
    int row = f4 >> 4;
    int c4  = (f4 & 15) << 2;
    float4 v = *reinterpret_cast<const float4*>(vsrc + row * D_ + c4);
    ushort4 u;
    u.x = (unsigned short)b16(v.x);
    u.y = (unsigned short)b16(v.y);
    u.z = (unsigned short)b16(v.z);
    u.w = (unsigned short)b16(v.w);
    *reinterpret_cast<ushort4*>(&lds[row * 68 + c4]) = u;
  }
  __syncthreads();
  unsigned short* dst = Vt + (size_t)bh * D_ * L_ + (size_t)kt * 64;
#pragma unroll
  for (int i = 0; i < 8; ++i) {
    int c  = i * 256 + t;
    int d  = c >> 5;
    int k2 = (c & 31) * 2;
    unsigned int lo = lds[(k2 + 0) * 68 + d];
    unsigned int hi = lds[(k2 + 1) * 68 + d];
    *reinterpret_cast<unsigned int*>(dst + d * L_ + k2) = lo | (hi << 16);
  }
}

// ---- fused sigmoid-attention: R1 structure + swapped-operand QK^T + vector epilogue ----
__global__ __launch_bounds__(256, 4) void attn3_kernel(
    const float* __restrict__ Q, const float* __restrict__ K,
    const int* __restrict__ M, const unsigned short* __restrict__ Vt,
    float* __restrict__ O, float* __restrict__ A) {
  __shared__ unsigned short Kl[64 * 64];
  __shared__ unsigned short Vl[64 * 64];
  __shared__ unsigned short Pl[64 * 64];

  // XCD-aware decode: all 16 heads of a (b,qt) mask-tile land on one XCD;
  // each XCD serves exactly one b. Bijective for grid 2048.
  int wg  = blockIdx.x;
  int xcd = wg & 7;
  int j   = wg >> 3;            // 0..255
  int g   = xcd * 16 + (j & 15);  // 0..127 : (b,qt) group
  int b   = g >> 5;
  int qt  = g & 31;
  int h   = j >> 4;             // 0..15
  int bh  = b * 16 + h;

  int t    = threadIdx.x;
  int lane = t & 63;
  int w    = t >> 6;
  int wr   = w >> 1;   // q quadrant
  int wc   = w & 1;    // k quadrant (S) / d quadrant (O)
  int lr   = lane & 15;
  int lg   = lane >> 4;

  // Q fragments, temperature folded in (×0.125 exact in bf16)
  short8 qf[2][2];
  const float* qbase = Q + ((size_t)bh * L_ + (size_t)qt * 64 + wr * 32) * D_;
#pragma unroll
  for (int m = 0; m < 2; ++m) {
#pragma unroll
    for (int ks = 0; ks < 2; ++ks) {
      const float4* p = reinterpret_cast<const float4*>(qbase + (m * 16 + lr) * D_ + ks * 32 + lg * 8);
      float4 a = p[0], c = p[1];
      qf[m][ks] = (short8){b16(a.x * 0.125f), b16(a.y * 0.125f), b16(a.z * 0.125f), b16(a.w * 0.125f),
                           b16(c.x * 0.125f), b16(c.y * 0.125f), b16(c.z * 0.125f), b16(c.w * 0.125f)};
    }
  }

  f32x4 o[2][2] = {};
  const int* mbase = M + (size_t)b * L_ * L_;
  float* abase = A + (size_t)bh * L_ * L_;
  const float* kbase0 = K + (size_t)bh * L_ * D_;
  const unsigned short* vbase0 = Vt + (size_t)bh * D_ * L_;
  int qrow = qt * 64 + wr * 32;

  for (int ki = 0; ki < 32; ++ki) {
    int k0 = ki * 64;

    // mask: one int4 per 16x16 tile (overlaps staging)
    int4 mv[2][2];
#pragma unroll
    for (int m = 0; m < 2; ++m)
#pragma unroll
      for (int n = 0; n < 2; ++n)
        mv[m][n] = *reinterpret_cast<const int4*>(
            mbase + (size_t)(qrow + m * 16 + lr) * L_ + k0 + wc * 32 + n * 16 + lg * 4);

    __syncthreads();  // previous iter's LDS readers done

    // ---- stage K tile (fp32 -> bf16, swizzled) ----
    const float* ksrc = kbase0 + (size_t)k0 * D_;
#pragma unroll
    for (int i = 0; i < 4; ++i) {
      int f4  = i * 256 + t;
      int row = f4 >> 4;
      int c4  = (f4 & 15) << 2;
      float4 v = *reinterpret_cast<const float4*>(ksrc + row * D_ + c4);
      ushort4 u;
      u.x = (unsigned short)b16(v.x);
      u.y = (unsigned short)b16(v.y);
      u.z = (unsigned short)b16(v.z);
      u.w = (unsigned short)b16(v.w);
      *reinterpret_cast<ushort4*>(&Kl[row * 64 + (c4 ^ ((row & 7) << 3))]) = u;
    }
    // ---- stage V^T tile (bf16, swizzled) ----
    const unsigned short* vsrc = vbase0 + k0;
#pragma unroll
    for (int i = 0; i < 2; ++i) {
      int gidx = i * 256 + t;
      int row  = gidx >> 3;
      int c0   = (gidx & 7) << 3;
      uint4 v = *reinterpret_cast<const uint4*>(vsrc + (size_t)row * L_ + c0);
      *reinterpret_cast<uint4*>(&Vl[row * 64 + (c0 ^ ((row & 7) << 3))]) = v;
    }
    __syncthreads();

    // ---- S^T = K Q^T : lane holds 4 consecutive k for one q ----
    f32x4 s[2][2] = {};
#pragma unroll
    for (int ks = 0; ks < 2; ++ks) {
      short8 kf[2];
#pragma unroll
      for (int n = 0; n < 2; ++n) {
        int row = wc * 32 + n * 16 + lr;   // key index
        int col = ks * 32 + lg * 8;        // d
        kf[n] = *reinterpret_cast<const short8*>(&Kl[row * 64 + (col ^ ((row & 7) << 3))]);
      }
#pragma unroll
      for (int m = 0; m < 2; ++m)
#pragma unroll
        for (int n = 0; n < 2; ++n)
          s[m][n] = __builtin_amdgcn_mfma_f32_16x16x32_bf16(kf[n], qf[m][ks], s[m][n], 0, 0, 0);
    }

    // ---- mask + fast sigmoid; attn f32x4 nt-store; P ushort4 LDS write ----
#pragma unroll
    for (int m = 0; m < 2; ++m) {
#pragma unroll
      for (int n = 0; n < 2; ++n) {
        f32x4 f;
        ushort4 u;
#pragma unroll
        for (int r = 0; r < 4; ++r) {
          float sv = s[m][n][r];
          float e  = __builtin_amdgcn_exp2f(sv * -1.44269504f);
          float at = ((&mv[m][n].x)[r] != 0)
                         ? __builtin_amdgcn_rcpf(1.0f + e)
                         : 0.0f;
          f[r] = at;
          (&u.x)[r] = (unsigned short)b16(at);
        }
        __builtin_nontemporal_store(f, reinterpret_cast<f32x4*>(
            abase + (size_t)(qrow + m * 16 + lr) * L_ + k0 + wc * 32 + n * 16 + lg * 4));
        int q  = wr * 32 + m * 16 + lr;
        int kl = wc * 32 + n * 16 + lg * 4;
        *reinterpret_cast<ushort4*>(&Pl[q * 64 + (kl ^ ((q & 7) << 3))]) = u;
      }
    }
    __syncthreads();  // P complete

    // ---- O += P V ----
#pragma unroll
    for (int ks = 0; ks < 2; ++ks) {
      short8 pf[2], vf[2];
#pragma unroll
      for (int m = 0; m < 2; ++m) {
        int row = wr * 32 + m * 16 + lr;   // q
        int col = ks * 32 + lg * 8;        // k
        pf[m] = *reinterpret_cast<const short8*>(&Pl[row * 64 + (col ^ ((row & 7) << 3))]);
      }
#pragma unroll
      for (int n = 0; n < 2; ++n) {
        int row = wc * 32 + n * 16 + lr;   // d
        int col = ks * 32 + lg * 8;        // k
        vf[n] = *reinterpret_cast<const short8*>(&Vl[row * 64 + (col ^ ((row & 7) << 3))]);
      }
#pragma unroll
      for (int m = 0; m < 2; ++m)
#pragma unroll
        for (int n = 0; n < 2; ++n)
          o[m][n] = __builtin_amdgcn_mfma_f32_16x16x32_bf16(pf[m], vf[n], o[m][n], 0, 0, 0);
    }
  }

  // ---- epilogue: write O ----
  float* obase = O + ((size_t)bh * L_ + (size_t)qt * 64 + wr * 32) * D_;
#pragma unroll
  for (int m = 0; m < 2; ++m)
#pragma unroll
    for (int n = 0; n < 2; ++n)
#pragma unroll
      for (int r = 0; r < 4; ++r)
        __builtin_nontemporal_store(o[m][n][r],
            &obase[(m * 16 + lg * 4 + r) * D_ + wc * 32 + n * 16 + lr]);
}

extern "C" void kernel_launch(void* const* d_in, const int* in_sizes, int n_in,
                              void* d_out, int out_size, void* d_ws, size_t ws_size,
                              hipStream_t stream) {
  (void)in_sizes; (void)n_in; (void)out_size; (void)ws_size;
  const float* Q = (const float*)d_in[0];
  const float* K = (const float*)d_in[1];
  const float* V = (const float*)d_in[2];
  const int*   M = (const int*)d_in[3];
  float* O = (float*)d_out;
  float* A = (float*)d_out + (size_t)BH * L_ * D_;
  unsigned short* Vt = (unsigned short*)d_ws;  // 16.8 MB scratch

  vt_kernel<<<BH * 32, 256, 0, stream>>>(V, Vt);
  attn3_kernel<<<BH * 32, 256, 0, stream>>>(Q, K, M, Vt, O, A);
}